// Round 3
// baseline (537.445 us; speedup 1.0000x reference)
//
#include <hip/hip_runtime.h>
#include <hip/hip_bf16.h>

// GATNet 2-layer GAT, N=50000, E=800000 (+N self loops).
// Round-2 diagnosis: persistent NaN likely = dtype mismatch (reference is pure
// float32; earlier rounds read inputs as bf16 -> garbage/NaN bf16 decodes).
// This round: runtime dtype probe + dual (f32 / bf16) templated pipelines.
// Internal buffers are always bf16 (packed); only d_in/d_out accesses differ.

typedef __attribute__((ext_vector_type(8))) short bf8_t;   // 8 x bf16 (4 VGPRs)
typedef __attribute__((ext_vector_type(4))) float f4_t;

__device__ inline short f2bf(float f) {
    return (short)__builtin_bit_cast(unsigned short, __float2bfloat16(f));
}
template<int MODE> __device__ inline float ldf(const void* p, size_t i) {
    if (MODE) return __bfloat162float(((const __hip_bfloat16*)p)[i]);
    else      return ((const float*)p)[i];
}
// 8 consecutive elements -> bf16x8 fragment
template<int MODE> __device__ inline bf8_t ld8(const void* p, size_t i) {
    if (MODE) {
        return *(const bf8_t*)((const short*)p + i);
    } else {
        const float* f = (const float*)p + i;
        bf8_t r;
        #pragma unroll
        for (int j = 0; j < 8; j++) r[j] = f2bf(f[j]);
        return r;
    }
}

// ---------------- dtype probe ----------------
// bf16 data: low 16 bits of each word = a bf16 ~N(0,1) -> exponent in [100,140].
// f32 data:  low 16 bits = mantissa bits -> uniform -> mostly wild exponents.
__global__ void k_detect(const unsigned int* __restrict__ xw, int* __restrict__ flag) {
    if (threadIdx.x != 0 || blockIdx.x != 0) return;
    int bad = 0;
    for (int i = 0; i < 256; i++) {
        unsigned int lo = xw[i * 13] & 0xffffu;
        int ex = (int)((lo >> 7) & 0xff);
        if (lo != 0u && (ex < 100 || ex > 140)) bad++;
    }
    *flag = (bad < 64) ? 1 : 0;    // 1 = bf16 data, 0 = f32 data
}

// ---------------- CSR build (dtype-independent) ----------------

__global__ void k_zero(int* __restrict__ a, int n) {
    int i = blockIdx.x * blockDim.x + threadIdx.x;
    if (i < n) a[i] = 0;
}

__global__ void k_count(const int* __restrict__ ei, int* __restrict__ deg, int E, int N) {
    int e = blockIdx.x * blockDim.x + threadIdx.x;
    if (e >= E + N) return;
    int dst = (e < E) ? ei[E + e] : (e - E);   // self-loops appended
    atomicAdd(&deg[dst], 1);
}

__global__ __launch_bounds__(1024) void k_scan(const int* __restrict__ deg,
                                               int* __restrict__ rowstart, int n) {
    __shared__ int buf[1024];
    __shared__ int carry;
    int tid = threadIdx.x;
    if (tid == 0) carry = 0;
    __syncthreads();
    for (int base = 0; base < n; base += 1024) {
        int i = base + tid;
        int v = (i < n) ? deg[i] : 0;
        buf[tid] = v;
        __syncthreads();
        for (int off = 1; off < 1024; off <<= 1) {
            int t = (tid >= off) ? buf[tid - off] : 0;
            __syncthreads();
            buf[tid] += t;
            __syncthreads();
        }
        if (i < n) rowstart[i] = carry + buf[tid] - v;   // exclusive
        int tot = buf[1023];
        __syncthreads();
        if (tid == 0) carry += tot;
        __syncthreads();
    }
    if (tid == 0) rowstart[n] = carry;
}

__global__ void k_fill(const int* __restrict__ ei, const int* __restrict__ rowstart,
                       int* __restrict__ cur, unsigned short* __restrict__ esrc,
                       int E, int N) {
    int e = blockIdx.x * blockDim.x + threadIdx.x;
    if (e >= E + N) return;
    int src, dst;
    if (e < E) { src = ei[e]; dst = ei[E + e]; }
    else       { src = e - E; dst = e - E; }
    int pos = rowstart[dst] + atomicAdd(&cur[dst], 1);
    esrc[pos] = (unsigned short)src;           // N < 65536
}

// ---------------- GEMMs (MFMA bf16 16x16x32) ----------------
// A-frag: lane holds A[m=lane&15][k=(lane>>4)*8+j]; B-frag: B[k][n=lane&15]
// C/D  : col=lane&15, row=(lane>>4)*4+reg  (m89-verified)

template<int MODE>
__global__ __launch_bounds__(256) void k_gemm0(
    const int* __restrict__ flag,
    const void* __restrict__ x, const void* __restrict__ W0, const void* __restrict__ lW0,
    __hip_bfloat16* __restrict__ h0, __hip_bfloat16* __restrict__ skipb, int N) {
    if (*flag != MODE) return;
    int wv = threadIdx.x >> 6, lane = threadIdx.x & 63;
    int rowbase = blockIdx.x * 64 + wv * 16;
    int m = lane & 15, q = lane >> 4;
    int arow = rowbase + m; if (arow >= N) arow = N - 1;
    bf8_t a[4];
    #pragma unroll
    for (int kb = 0; kb < 4; kb++)
        a[kb] = ld8<MODE>(x, (size_t)arow * 128 + kb * 32 + q * 8);
    for (int ct = 0; ct < 16; ct++) {
        const void* Wp = (ct < 8) ? W0 : lW0;
        int cb = (ct & 7) * 16;
        f4_t acc = {0.f, 0.f, 0.f, 0.f};
        #pragma unroll
        for (int kb = 0; kb < 4; kb++) {
            bf8_t b = ld8<MODE>(Wp, (size_t)(cb + m) * 128 + kb * 32 + q * 8);
            acc = __builtin_amdgcn_mfma_f32_16x16x32_bf16(a[kb], b, acc, 0, 0, 0);
        }
        #pragma unroll
        for (int r = 0; r < 4; r++) {
            int row = rowbase + q * 4 + r;
            if (row < N) {
                int col = cb + m;
                if (ct < 8) h0[(size_t)row * 128 + col]    = __float2bfloat16(acc[r]);
                else        skipb[(size_t)row * 128 + col] = __float2bfloat16(acc[r]);
            }
        }
    }
}

template<int MODE>
__global__ __launch_bounds__(256) void k_gemm1(
    const int* __restrict__ flag,
    const __hip_bfloat16* __restrict__ hin,       // internal bf16
    const void* __restrict__ W1, const void* __restrict__ lW1,
    __hip_bfloat16* __restrict__ h1, void* __restrict__ skipb /* = d_out */, int N) {
    if (*flag != MODE) return;
    int wv = threadIdx.x >> 6, lane = threadIdx.x & 63;
    int rowbase = blockIdx.x * 64 + wv * 16;
    int m = lane & 15, q = lane >> 4;
    int arow = rowbase + m; if (arow >= N) arow = N - 1;
    bf8_t a[4];
    #pragma unroll
    for (int kb = 0; kb < 4; kb++)
        a[kb] = ld8<1>(hin, (size_t)arow * 128 + kb * 32 + q * 8);
    #pragma unroll
    for (int ct = 0; ct < 4; ct++) {
        const void* Wp = (ct < 2) ? W1 : lW1;
        int cb = (ct & 1) * 16;
        f4_t acc = {0.f, 0.f, 0.f, 0.f};
        #pragma unroll
        for (int kb = 0; kb < 4; kb++) {
            bf8_t b = ld8<MODE>(Wp, (size_t)(cb + m) * 128 + kb * 32 + q * 8);
            acc = __builtin_amdgcn_mfma_f32_16x16x32_bf16(a[kb], b, acc, 0, 0, 0);
        }
        #pragma unroll
        for (int r = 0; r < 4; r++) {
            int row = rowbase + q * 4 + r;
            if (row < N) {
                size_t idx = (size_t)row * 32 + cb + m;
                if (ct < 2) h1[idx] = __float2bfloat16(acc[r]);
                else if (MODE) ((__hip_bfloat16*)skipb)[idx] = __float2bfloat16(acc[r]);
                else           ((float*)skipb)[idx] = acc[r];
            }
        }
    }
}

// ---------------- attention logits ----------------

template<int MODE>
__global__ void k_att0(const int* __restrict__ flag,
                       const __hip_bfloat16* __restrict__ h0,
                       const void* __restrict__ as0, const void* __restrict__ ad0,
                       float* __restrict__ a0s, float* __restrict__ a0d, int N) {
    if (*flag != MODE) return;
    int gid = blockIdx.x * blockDim.x + threadIdx.x;
    if (gid >= N * 4) return;
    int hd = gid & 3, n = gid >> 2;
    float s = 0.f, d = 0.f;
    #pragma unroll
    for (int c = 0; c < 32; c++) {
        float h = __bfloat162float(h0[(size_t)n * 128 + hd * 32 + c]);
        s += h * ldf<MODE>(as0, hd * 32 + c);
        d += h * ldf<MODE>(ad0, hd * 32 + c);
    }
    a0s[gid] = s; a0d[gid] = d;
}

template<int MODE>
__global__ void k_att1(const int* __restrict__ flag,
                       const __hip_bfloat16* __restrict__ h1,
                       const void* __restrict__ as1, const void* __restrict__ ad1,
                       float* __restrict__ a1s, float* __restrict__ a1d, int N) {
    if (*flag != MODE) return;
    int i = blockIdx.x * blockDim.x + threadIdx.x;
    if (i >= N) return;
    float s = 0.f, d = 0.f;
    #pragma unroll
    for (int c = 0; c < 32; c++) {
        float h = __bfloat162float(h1[(size_t)i * 32 + c]);
        s += h * ldf<MODE>(as1, c);
        d += h * ldf<MODE>(ad1, c);
    }
    a1s[i] = s; a1d[i] = d;
}

// ---------------- aggregation (fused softmax) ----------------

// one wave per node; lane handles channels 2*lane, 2*lane+1; head = lane>>4
template<int MODE>
__global__ __launch_bounds__(256) void k_agg0(
    const int* __restrict__ flag,
    const int* __restrict__ rowstart, const unsigned short* __restrict__ esrc,
    const unsigned int* __restrict__ h0u,              // h0 packed bf16x2
    const float* __restrict__ a0s, const float* __restrict__ a0d,
    const void* __restrict__ bias0, const void* __restrict__ linb0,
    unsigned int* __restrict__ h1in_u,                 // in: skip0 bf16, out: ELU result
    int n) {
    if (*flag != MODE) return;
    int node = (blockIdx.x * 256 + threadIdx.x) >> 6;
    int lane = threadIdx.x & 63;
    if (node >= n) return;
    int hd = lane >> 4;
    float ad = a0d[node * 4 + hd];
    int s0 = rowstart[node], s1 = rowstart[node + 1];
    float acc0 = 0.f, acc1 = 0.f, den = 0.f;
    for (int i = s0; i < s1; i++) {
        int src = (int)esrc[i];
        float e = a0s[src * 4 + hd] + ad;
        e = (e > 0.f) ? e : 0.2f * e;          // leaky_relu(0.2)
        e = fminf(e, 80.f);                    // NaN guard
        float wgt = __expf(e);                 // softmax w/o max-shift
        den += wgt;
        unsigned int p = h0u[(size_t)src * 64 + lane];
        acc0 += wgt * __uint_as_float(p << 16);
        acc1 += wgt * __uint_as_float(p & 0xffff0000u);
    }
    float inv = 1.0f / (den + 1e-16f);
    int c0 = lane * 2;
    unsigned int sp = h1in_u[(size_t)node * 64 + lane];   // skip0 (bf16 pair)
    float o0 = acc0 * inv + __uint_as_float(sp << 16)
             + ldf<MODE>(bias0, c0) + ldf<MODE>(linb0, c0);
    float o1 = acc1 * inv + __uint_as_float(sp & 0xffff0000u)
             + ldf<MODE>(bias0, c0 + 1) + ldf<MODE>(linb0, c0 + 1);
    o0 = (o0 > 0.f) ? o0 : (__expf(o0) - 1.f);  // ELU
    o1 = (o1 > 0.f) ? o1 : (__expf(o1) - 1.f);
    unsigned int b0 = (unsigned int)(unsigned short)f2bf(o0);
    unsigned int b1 = (unsigned int)(unsigned short)f2bf(o1);
    h1in_u[(size_t)node * 64 + lane] = b0 | (b1 << 16);
}

// 32 threads per node; d_out holds skip1 on entry, final on exit
template<int MODE>
__global__ __launch_bounds__(256) void k_agg1(
    const int* __restrict__ flag,
    const int* __restrict__ rowstart, const unsigned short* __restrict__ esrc,
    const __hip_bfloat16* __restrict__ h1,
    const float* __restrict__ a1s, const float* __restrict__ a1d,
    const void* __restrict__ bias1, const void* __restrict__ linb1,
    void* __restrict__ out, int n) {
    if (*flag != MODE) return;
    int gid = blockIdx.x * blockDim.x + threadIdx.x;
    int node = gid >> 5, c = gid & 31;
    if (node >= n) return;
    float ad = a1d[node];
    int s0 = rowstart[node], s1 = rowstart[node + 1];
    float acc = 0.f, den = 0.f;
    for (int i = s0; i < s1; i++) {
        int src = (int)esrc[i];
        float e = a1s[src] + ad;
        e = (e > 0.f) ? e : 0.2f * e;
        e = fminf(e, 80.f);
        float wgt = __expf(e);
        den += wgt;
        acc += wgt * __bfloat162float(h1[(size_t)src * 32 + c]);
    }
    size_t idx = (size_t)node * 32 + c;
    float o = acc / (den + 1e-16f) + ldf<MODE>(out, idx)    // skip1
            + ldf<MODE>(bias1, c) + ldf<MODE>(linb1, c);
    if (MODE) ((__hip_bfloat16*)out)[idx] = __float2bfloat16(o);
    else      ((float*)out)[idx] = o;
}

// ---------------- launch ----------------

extern "C" void kernel_launch(void* const* d_in, const int* in_sizes, int n_in,
                              void* d_out, int out_size, void* d_ws, size_t ws_size,
                              hipStream_t stream) {
    const void* x   = d_in[0];
    const int*  ei  = (const int*)d_in[1];
    const void* W0  = d_in[2];
    const void* as0 = d_in[3];
    const void* ad0 = d_in[4];
    const void* b0  = d_in[5];
    const void* lW0 = d_in[6];
    const void* lb0 = d_in[7];
    const void* W1  = d_in[8];
    const void* as1 = d_in[9];
    const void* ad1 = d_in[10];
    const void* b1  = d_in[11];
    const void* lW1 = d_in[12];
    const void* lb1 = d_in[13];

    const int N = in_sizes[0] / 128;
    const int E = in_sizes[1] / 2;
    const int T = E + N;

    // workspace carve-up (256B aligned), ~29.3 MB total
    char* w = (char*)d_ws;
    auto alloc = [&](size_t bytes) -> char* {
        char* p = w; w += (bytes + 255) / 256 * 256; return p;
    };
    int* flag      = (int*)alloc(256);
    int* rowstart  = (int*)alloc((size_t)(N + 1) * 4);
    int* cnt       = (int*)alloc((size_t)N * 4);
    unsigned short* esrc = (unsigned short*)alloc((size_t)T * 2);
    float* aS      = (float*)alloc((size_t)N * 4 * 4);
    float* aD      = (float*)alloc((size_t)N * 4 * 4);
    __hip_bfloat16* hbuf = (__hip_bfloat16*)alloc((size_t)N * 128 * 2); // h0 / h1
    __hip_bfloat16* h1in = (__hip_bfloat16*)alloc((size_t)N * 128 * 2); // skip0 -> ELU out

    k_detect<<<1, 64, 0, stream>>>((const unsigned int*)x, flag);

    // CSR build (shared)
    k_zero<<<(N + 255) / 256, 256, 0, stream>>>(cnt, N);
    k_count<<<(T + 255) / 256, 256, 0, stream>>>(ei, cnt, E, N);
    k_scan<<<1, 1024, 0, stream>>>(cnt, rowstart, N);
    k_zero<<<(N + 255) / 256, 256, 0, stream>>>(cnt, N);
    k_fill<<<(T + 255) / 256, 256, 0, stream>>>(ei, rowstart, cnt, esrc, E, N);

    int gN64 = (N + 63) / 64, gA0 = (N * 4 + 255) / 256;
    int gAgg0 = (N + 3) / 4, gN256 = (N + 255) / 256, gAgg1 = (N * 32 + 255) / 256;

    // layer 0
    k_gemm0<0><<<gN64, 256, 0, stream>>>(flag, x, W0, lW0, hbuf, h1in, N);
    k_gemm0<1><<<gN64, 256, 0, stream>>>(flag, x, W0, lW0, hbuf, h1in, N);
    k_att0<0><<<gA0, 256, 0, stream>>>(flag, hbuf, as0, ad0, aS, aD, N);
    k_att0<1><<<gA0, 256, 0, stream>>>(flag, hbuf, as0, ad0, aS, aD, N);
    k_agg0<0><<<gAgg0, 256, 0, stream>>>(flag, rowstart, esrc, (const unsigned int*)hbuf,
                                         aS, aD, b0, lb0, (unsigned int*)h1in, N);
    k_agg0<1><<<gAgg0, 256, 0, stream>>>(flag, rowstart, esrc, (const unsigned int*)hbuf,
                                         aS, aD, b0, lb0, (unsigned int*)h1in, N);
    // layer 1 (h1 reuses hbuf; skip1 lives in d_out)
    k_gemm1<0><<<gN64, 256, 0, stream>>>(flag, h1in, W1, lW1, hbuf, d_out, N);
    k_gemm1<1><<<gN64, 256, 0, stream>>>(flag, h1in, W1, lW1, hbuf, d_out, N);
    k_att1<0><<<gN256, 256, 0, stream>>>(flag, hbuf, as1, ad1, aS, aD, N);
    k_att1<1><<<gN256, 256, 0, stream>>>(flag, hbuf, as1, ad1, aS, aD, N);
    k_agg1<0><<<gAgg1, 256, 0, stream>>>(flag, rowstart, esrc, hbuf, aS, aD,
                                         b1, lb1, d_out, N);
    k_agg1<1><<<gAgg1, 256, 0, stream>>>(flag, rowstart, esrc, hbuf, aS, aD,
                                         b1, lb1, d_out, N);
}

// Round 4
// 309.135 us; speedup vs baseline: 1.7385x; 1.7385x over previous
//
#include <hip/hip_runtime.h>
#include <hip/hip_bf16.h>

// GATNet 2-layer GAT, N=50000, E=800000 (+N self loops).
// Confirmed round 3: inputs/outputs are FLOAT32 (bf16 read => NaN; probe-selected
// f32 path passed). Internal compute: bf16 MFMA with f32 accumulate.
// Round-4 changes: hardcode f32 (drop probe + dual launches), hierarchical scan
// (94us -> ~8us), unroll-4 gather pipelines in agg0/agg1, prepped bf16 weights.

typedef __attribute__((ext_vector_type(8))) short bf8_t;   // 8 x bf16 (4 VGPRs)
typedef __attribute__((ext_vector_type(4))) float f4_t;

__device__ inline short f2bf(float f) {
    return (short)__builtin_bit_cast(unsigned short, __float2bfloat16(f));
}
// 8 consecutive f32 -> bf16x8 fragment
__device__ inline bf8_t ld8f(const float* p) {
    bf8_t r;
    #pragma unroll
    for (int j = 0; j < 8; j++) r[j] = f2bf(p[j]);
    return r;
}
__device__ inline float blo(unsigned int p) { return __uint_as_float(p << 16); }
__device__ inline float bhi(unsigned int p) { return __uint_as_float(p & 0xffff0000u); }

// ---------------- weight prep: f32 -> bf16 (once per call) ----------------
__global__ void k_prep(const float* __restrict__ W0, const float* __restrict__ lW0,
                       const float* __restrict__ W1, const float* __restrict__ lW1,
                       short* __restrict__ Wc0, short* __restrict__ lWc0,
                       short* __restrict__ Wc1, short* __restrict__ lWc1) {
    int i = blockIdx.x * blockDim.x + threadIdx.x;     // 40960 total
    if (i < 16384)       Wc0[i]          = f2bf(W0[i]);
    else if (i < 32768)  lWc0[i - 16384] = f2bf(lW0[i - 16384]);
    else if (i < 36864)  Wc1[i - 32768]  = f2bf(W1[i - 32768]);
    else if (i < 40960)  lWc1[i - 36864] = f2bf(lW1[i - 36864]);
}

// ---------------- CSR build ----------------

__global__ void k_zero(int* __restrict__ a, int n) {
    int i = blockIdx.x * blockDim.x + threadIdx.x;
    if (i < n) a[i] = 0;
}

__global__ void k_count(const int* __restrict__ ei, int* __restrict__ deg, int E, int N) {
    int e = blockIdx.x * blockDim.x + threadIdx.x;
    if (e >= E + N) return;
    int dst = (e < E) ? ei[E + e] : (e - E);   // self-loops appended
    atomicAdd(&deg[dst], 1);
}

// hierarchical exclusive scan: (1) per-block local scan + block sums
__global__ __launch_bounds__(1024) void k_scan1(const int* __restrict__ deg,
                                                int* __restrict__ rowstart,
                                                int* __restrict__ bsum, int n) {
    __shared__ int buf[1024];
    int tid = threadIdx.x, i = blockIdx.x * 1024 + tid;
    int v = (i < n) ? deg[i] : 0;
    buf[tid] = v;
    __syncthreads();
    for (int off = 1; off < 1024; off <<= 1) {
        int t = (tid >= off) ? buf[tid - off] : 0;
        __syncthreads();
        buf[tid] += t;
        __syncthreads();
    }
    if (i < n) rowstart[i] = buf[tid] - v;     // local exclusive
    if (tid == 1023) bsum[blockIdx.x] = buf[1023];
}

// (2) scan the <=64 block sums in one wave
__global__ void k_scan2(const int* __restrict__ bsum, int* __restrict__ bcar,
                        int* __restrict__ rowstart, int nb, int n) {
    int lane = threadIdx.x;
    int v = (lane < nb) ? bsum[lane] : 0;
    int s = v;
    #pragma unroll
    for (int off = 1; off < 64; off <<= 1) {
        int t = __shfl_up(s, off);
        if (lane >= off) s += t;
    }
    if (lane < nb) bcar[lane] = s - v;         // exclusive carry per block
    if (lane == 63) rowstart[n] = s;           // grand total
}

// (3) add carries; also init fill-cursor = rowstart
__global__ __launch_bounds__(1024) void k_scan3(int* __restrict__ rowstart,
                                                const int* __restrict__ bcar,
                                                int* __restrict__ cur, int n) {
    int i = blockIdx.x * 1024 + threadIdx.x;
    if (i < n) {
        int r = rowstart[i] + bcar[blockIdx.x];
        rowstart[i] = r;
        cur[i] = r;
    }
}

__global__ void k_fill(const int* __restrict__ ei, int* __restrict__ cur,
                       unsigned short* __restrict__ esrc, int E, int N) {
    int e = blockIdx.x * blockDim.x + threadIdx.x;
    if (e >= E + N) return;
    int src, dst;
    if (e < E) { src = ei[e]; dst = ei[E + e]; }
    else       { src = e - E; dst = e - E; }
    int pos = atomicAdd(&cur[dst], 1);
    esrc[pos] = (unsigned short)src;           // N < 65536
}

// ---------------- GEMMs (MFMA bf16 16x16x32) ----------------
// A-frag: lane holds A[m=lane&15][k=(lane>>4)*8+j]; B-frag: B[k][n=lane&15]
// C/D  : col=lane&15, row=(lane>>4)*4+reg  (m89-verified)

__global__ __launch_bounds__(256) void k_gemm0(
    const float* __restrict__ x,
    const short* __restrict__ Wc0, const short* __restrict__ lWc0,
    __hip_bfloat16* __restrict__ h0, __hip_bfloat16* __restrict__ skipb, int N) {
    int wv = threadIdx.x >> 6, lane = threadIdx.x & 63;
    int rowbase = blockIdx.x * 64 + wv * 16;
    int m = lane & 15, q = lane >> 4;
    int arow = rowbase + m; if (arow >= N) arow = N - 1;
    bf8_t a[4];
    #pragma unroll
    for (int kb = 0; kb < 4; kb++)
        a[kb] = ld8f(x + (size_t)arow * 128 + kb * 32 + q * 8);
    for (int ct = 0; ct < 16; ct++) {
        const short* Wp = (ct < 8) ? Wc0 : lWc0;
        int cb = (ct & 7) * 16;
        f4_t acc = {0.f, 0.f, 0.f, 0.f};
        #pragma unroll
        for (int kb = 0; kb < 4; kb++) {
            bf8_t b = *(const bf8_t*)(Wp + (size_t)(cb + m) * 128 + kb * 32 + q * 8);
            acc = __builtin_amdgcn_mfma_f32_16x16x32_bf16(a[kb], b, acc, 0, 0, 0);
        }
        #pragma unroll
        for (int r = 0; r < 4; r++) {
            int row = rowbase + q * 4 + r;
            if (row < N) {
                int col = cb + m;
                if (ct < 8) h0[(size_t)row * 128 + col]    = __float2bfloat16(acc[r]);
                else        skipb[(size_t)row * 128 + col] = __float2bfloat16(acc[r]);
            }
        }
    }
}

__global__ __launch_bounds__(256) void k_gemm1(
    const __hip_bfloat16* __restrict__ hin,
    const short* __restrict__ Wc1, const short* __restrict__ lWc1,
    __hip_bfloat16* __restrict__ h1, float* __restrict__ skipb /* = d_out */, int N) {
    int wv = threadIdx.x >> 6, lane = threadIdx.x & 63;
    int rowbase = blockIdx.x * 64 + wv * 16;
    int m = lane & 15, q = lane >> 4;
    int arow = rowbase + m; if (arow >= N) arow = N - 1;
    const short* xs = (const short*)hin;
    bf8_t a[4];
    #pragma unroll
    for (int kb = 0; kb < 4; kb++)
        a[kb] = *(const bf8_t*)(xs + (size_t)arow * 128 + kb * 32 + q * 8);
    #pragma unroll
    for (int ct = 0; ct < 4; ct++) {
        const short* Wp = (ct < 2) ? Wc1 : lWc1;
        int cb = (ct & 1) * 16;
        f4_t acc = {0.f, 0.f, 0.f, 0.f};
        #pragma unroll
        for (int kb = 0; kb < 4; kb++) {
            bf8_t b = *(const bf8_t*)(Wp + (size_t)(cb + m) * 128 + kb * 32 + q * 8);
            acc = __builtin_amdgcn_mfma_f32_16x16x32_bf16(a[kb], b, acc, 0, 0, 0);
        }
        #pragma unroll
        for (int r = 0; r < 4; r++) {
            int row = rowbase + q * 4 + r;
            if (row < N) {
                size_t idx = (size_t)row * 32 + cb + m;
                if (ct < 2) h1[idx] = __float2bfloat16(acc[r]);
                else        skipb[idx] = acc[r];
            }
        }
    }
}

// ---------------- attention logits ----------------

__global__ void k_att0(const __hip_bfloat16* __restrict__ h0,
                       const float* __restrict__ as0, const float* __restrict__ ad0,
                       float* __restrict__ a0s, float* __restrict__ a0d, int N) {
    int gid = blockIdx.x * blockDim.x + threadIdx.x;
    if (gid >= N * 4) return;
    int hd = gid & 3, n = gid >> 2;
    float s = 0.f, d = 0.f;
    #pragma unroll
    for (int c = 0; c < 32; c++) {
        float h = __bfloat162float(h0[(size_t)n * 128 + hd * 32 + c]);
        s += h * as0[hd * 32 + c];
        d += h * ad0[hd * 32 + c];
    }
    a0s[gid] = s; a0d[gid] = d;
}

__global__ void k_att1(const __hip_bfloat16* __restrict__ h1,
                       const float* __restrict__ as1, const float* __restrict__ ad1,
                       float* __restrict__ a1s, float* __restrict__ a1d, int N) {
    int i = blockIdx.x * blockDim.x + threadIdx.x;
    if (i >= N) return;
    float s = 0.f, d = 0.f;
    #pragma unroll
    for (int c = 0; c < 32; c++) {
        float h = __bfloat162float(h1[(size_t)i * 32 + c]);
        s += h * as1[c];
        d += h * ad1[c];
    }
    a1s[i] = s; a1d[i] = d;
}

// ---------------- aggregation (fused softmax, unroll-4 gather pipeline) --------

__device__ inline float lrexp(float e) {
    e = (e > 0.f) ? e : 0.2f * e;          // leaky_relu(0.2)
    return __expf(fminf(e, 80.f));         // guard never binds on sane data
}

// one wave per node; lane handles channels 2*lane, 2*lane+1; head = lane>>4
__global__ __launch_bounds__(256) void k_agg0(
    const int* __restrict__ rowstart, const unsigned short* __restrict__ esrc,
    const unsigned int* __restrict__ h0u,              // h0 packed bf16x2
    const float* __restrict__ a0s, const float* __restrict__ a0d,
    const float* __restrict__ bias0, const float* __restrict__ linb0,
    unsigned int* __restrict__ h1in_u,                 // in: skip0 bf16, out: ELU result
    int n) {
    int node = (blockIdx.x * 256 + threadIdx.x) >> 6;
    int lane = threadIdx.x & 63;
    if (node >= n) return;
    int hd = lane >> 4;
    float ad = a0d[node * 4 + hd];
    int s0 = rowstart[node], s1 = rowstart[node + 1];
    float den = 0.f, acc0 = 0.f, acc1 = 0.f;
    float denb = 0.f, acc0b = 0.f, acc1b = 0.f;
    int i = s0;
    for (; i + 3 < s1; i += 4) {
        int sA = esrc[i], sB = esrc[i + 1], sC = esrc[i + 2], sD = esrc[i + 3];
        float eA = a0s[sA * 4 + hd] + ad;
        float eB = a0s[sB * 4 + hd] + ad;
        float eC = a0s[sC * 4 + hd] + ad;
        float eD = a0s[sD * 4 + hd] + ad;
        unsigned int pA = h0u[(size_t)sA * 64 + lane];
        unsigned int pB = h0u[(size_t)sB * 64 + lane];
        unsigned int pC = h0u[(size_t)sC * 64 + lane];
        unsigned int pD = h0u[(size_t)sD * 64 + lane];
        float wA = lrexp(eA), wB = lrexp(eB), wC = lrexp(eC), wD = lrexp(eD);
        den  += wA + wC;  denb += wB + wD;
        acc0  += wA * blo(pA); acc1  += wA * bhi(pA);
        acc0b += wB * blo(pB); acc1b += wB * bhi(pB);
        acc0  += wC * blo(pC); acc1  += wC * bhi(pC);
        acc0b += wD * blo(pD); acc1b += wD * bhi(pD);
    }
    for (; i < s1; i++) {
        int s = esrc[i];
        float wgt = lrexp(a0s[s * 4 + hd] + ad);
        unsigned int p = h0u[(size_t)s * 64 + lane];
        den += wgt; acc0 += wgt * blo(p); acc1 += wgt * bhi(p);
    }
    den += denb; acc0 += acc0b; acc1 += acc1b;
    float inv = 1.0f / (den + 1e-16f);
    int c0 = lane * 2;
    unsigned int sp = h1in_u[(size_t)node * 64 + lane];   // skip0 (bf16 pair)
    float o0 = acc0 * inv + blo(sp) + bias0[c0]     + linb0[c0];
    float o1 = acc1 * inv + bhi(sp) + bias0[c0 + 1] + linb0[c0 + 1];
    o0 = (o0 > 0.f) ? o0 : (__expf(o0) - 1.f);  // ELU
    o1 = (o1 > 0.f) ? o1 : (__expf(o1) - 1.f);
    unsigned int r0 = (unsigned int)(unsigned short)f2bf(o0);
    unsigned int r1 = (unsigned int)(unsigned short)f2bf(o1);
    h1in_u[(size_t)node * 64 + lane] = r0 | (r1 << 16);
}

// 32 threads per node; d_out (f32) holds skip1 on entry, final on exit
__global__ __launch_bounds__(256) void k_agg1(
    const int* __restrict__ rowstart, const unsigned short* __restrict__ esrc,
    const __hip_bfloat16* __restrict__ h1,
    const float* __restrict__ a1s, const float* __restrict__ a1d,
    const float* __restrict__ bias1, const float* __restrict__ linb1,
    float* __restrict__ out, int n) {
    int gid = blockIdx.x * blockDim.x + threadIdx.x;
    int node = gid >> 5, c = gid & 31;
    if (node >= n) return;
    float ad = a1d[node];
    int s0 = rowstart[node], s1 = rowstart[node + 1];
    float den = 0.f, acc = 0.f, denb = 0.f, accb = 0.f;
    const unsigned short* h1u = (const unsigned short*)h1;
    int i = s0;
    for (; i + 3 < s1; i += 4) {
        int sA = esrc[i], sB = esrc[i + 1], sC = esrc[i + 2], sD = esrc[i + 3];
        float eA = a1s[sA] + ad, eB = a1s[sB] + ad, eC = a1s[sC] + ad, eD = a1s[sD] + ad;
        unsigned int hA = h1u[(size_t)sA * 32 + c];
        unsigned int hB = h1u[(size_t)sB * 32 + c];
        unsigned int hC = h1u[(size_t)sC * 32 + c];
        unsigned int hD = h1u[(size_t)sD * 32 + c];
        float wA = lrexp(eA), wB = lrexp(eB), wC = lrexp(eC), wD = lrexp(eD);
        den  += wA + wC;  denb += wB + wD;
        acc  += wA * __uint_as_float(hA << 16);
        accb += wB * __uint_as_float(hB << 16);
        acc  += wC * __uint_as_float(hC << 16);
        accb += wD * __uint_as_float(hD << 16);
    }
    for (; i < s1; i++) {
        int s = esrc[i];
        float wgt = lrexp(a1s[s] + ad);
        den += wgt;
        acc += wgt * __uint_as_float((unsigned int)h1u[(size_t)s * 32 + c] << 16);
    }
    den += denb; acc += accb;
    size_t idx = (size_t)node * 32 + c;
    float o = acc / (den + 1e-16f) + out[idx] + bias1[c] + linb1[c];
    out[idx] = o;
}

// ---------------- launch ----------------

extern "C" void kernel_launch(void* const* d_in, const int* in_sizes, int n_in,
                              void* d_out, int out_size, void* d_ws, size_t ws_size,
                              hipStream_t stream) {
    const float* x   = (const float*)d_in[0];
    const int*   ei  = (const int*)d_in[1];
    const float* W0  = (const float*)d_in[2];
    const float* as0 = (const float*)d_in[3];
    const float* ad0 = (const float*)d_in[4];
    const float* b0  = (const float*)d_in[5];
    const float* lW0 = (const float*)d_in[6];
    const float* lb0 = (const float*)d_in[7];
    const float* W1  = (const float*)d_in[8];
    const float* as1 = (const float*)d_in[9];
    const float* ad1 = (const float*)d_in[10];
    const float* b1  = (const float*)d_in[11];
    const float* lW1 = (const float*)d_in[12];
    const float* lb1 = (const float*)d_in[13];
    float* out = (float*)d_out;

    const int N = in_sizes[0] / 128;
    const int E = in_sizes[1] / 2;
    const int T = E + N;
    const int NB = (N + 1023) / 1024;   // scan blocks (49)

    // workspace carve-up (256B aligned), ~29.5 MB
    char* w = (char*)d_ws;
    auto alloc = [&](size_t bytes) -> char* {
        char* p = w; w += (bytes + 255) / 256 * 256; return p;
    };
    int* rowstart  = (int*)alloc((size_t)(N + 1) * 4);
    int* cnt       = (int*)alloc((size_t)N * 4);          // deg, then fill-cursor
    int* bsum      = (int*)alloc(64 * 4);
    int* bcar      = (int*)alloc(64 * 4);
    unsigned short* esrc = (unsigned short*)alloc((size_t)T * 2);
    float* aS      = (float*)alloc((size_t)N * 4 * 4);    // layer0 [N,4]; layer1 [N]
    float* aD      = (float*)alloc((size_t)N * 4 * 4);
    __hip_bfloat16* hbuf = (__hip_bfloat16*)alloc((size_t)N * 128 * 2); // h0 / h1
    __hip_bfloat16* h1in = (__hip_bfloat16*)alloc((size_t)N * 128 * 2); // skip0 -> ELU
    short* Wc0  = (short*)alloc(16384 * 2);
    short* lWc0 = (short*)alloc(16384 * 2);
    short* Wc1  = (short*)alloc(4096 * 2);
    short* lWc1 = (short*)alloc(4096 * 2);

    // weight prep (independent of CSR)
    k_prep<<<160, 256, 0, stream>>>(W0, lW0, W1, lW1, Wc0, lWc0, Wc1, lWc1);

    // CSR build
    k_zero<<<(N + 255) / 256, 256, 0, stream>>>(cnt, N);
    k_count<<<(T + 255) / 256, 256, 0, stream>>>(ei, cnt, E, N);
    k_scan1<<<NB, 1024, 0, stream>>>(cnt, rowstart, bsum, N);
    k_scan2<<<1, 64, 0, stream>>>(bsum, bcar, rowstart, NB, N);
    k_scan3<<<NB, 1024, 0, stream>>>(rowstart, bcar, cnt, N);
    k_fill<<<(T + 255) / 256, 256, 0, stream>>>(ei, cnt, esrc, E, N);

    // layer 0
    k_gemm0<<<(N + 63) / 64, 256, 0, stream>>>(x, Wc0, lWc0, hbuf, h1in, N);
    k_att0<<<(N * 4 + 255) / 256, 256, 0, stream>>>(hbuf, as0, ad0, aS, aD, N);
    k_agg0<<<(N + 3) / 4, 256, 0, stream>>>(rowstart, esrc, (const unsigned int*)hbuf,
                                            aS, aD, b0, lb0, (unsigned int*)h1in, N);
    // layer 1 (h1 reuses hbuf; skip1 lives in d_out f32)
    k_gemm1<<<(N + 63) / 64, 256, 0, stream>>>(h1in, Wc1, lWc1, hbuf, out, N);
    k_att1<<<(N + 255) / 256, 256, 0, stream>>>(hbuf, as1, ad1, aS, aD, N);
    k_agg1<<<(N * 32 + 255) / 256, 256, 0, stream>>>(rowstart, esrc, hbuf, aS, aD,
                                                     b1, lb1, out, N);
}

// Round 5
// 305.091 us; speedup vs baseline: 1.7616x; 1.0133x over previous
//
#include <hip/hip_runtime.h>
#include <hip/hip_bf16.h>

// GATNet 2-layer GAT, N=50000, E=800000 (+N self loops). f32 in/out (confirmed
// round 3), bf16 MFMA internally.
// Round-5: att0/att1 fused into gemm0/gemm1 (cross-lane reduce of MFMA acc),
// agg0 unroll-8, agg1 one-wave-per-node (split halves + shfl_xor combine),
// vectorized float4 x-loads in gemm0.

typedef __attribute__((ext_vector_type(8))) short bf8_t;   // 8 x bf16 (4 VGPRs)
typedef __attribute__((ext_vector_type(4))) float f4_t;

__device__ inline short f2bf(float f) {
    return (short)__builtin_bit_cast(unsigned short, __float2bfloat16(f));
}
__device__ inline float blo(unsigned int p) { return __uint_as_float(p << 16); }
__device__ inline float bhi(unsigned int p) { return __uint_as_float(p & 0xffff0000u); }
__device__ inline float lrexp(float e) {
    e = (e > 0.f) ? e : 0.2f * e;          // leaky_relu(0.2); |e|<~12 -> exp safe
    return __expf(e);
}

// ---------------- weight prep: f32 -> bf16 (once per call) ----------------
__global__ void k_prep(const float* __restrict__ W0, const float* __restrict__ lW0,
                       const float* __restrict__ W1, const float* __restrict__ lW1,
                       short* __restrict__ Wc0, short* __restrict__ lWc0,
                       short* __restrict__ Wc1, short* __restrict__ lWc1) {
    int i = blockIdx.x * blockDim.x + threadIdx.x;     // 40960 total
    if (i < 16384)       Wc0[i]          = f2bf(W0[i]);
    else if (i < 32768)  lWc0[i - 16384] = f2bf(lW0[i - 16384]);
    else if (i < 36864)  Wc1[i - 32768]  = f2bf(W1[i - 32768]);
    else if (i < 40960)  lWc1[i - 36864] = f2bf(lW1[i - 36864]);
}

// ---------------- CSR build ----------------

__global__ void k_zero(int* __restrict__ a, int n) {
    int i = blockIdx.x * blockDim.x + threadIdx.x;
    if (i < n) a[i] = 0;
}

__global__ void k_count(const int* __restrict__ ei, int* __restrict__ deg, int E, int N) {
    int e = blockIdx.x * blockDim.x + threadIdx.x;
    if (e >= E + N) return;
    int dst = (e < E) ? ei[E + e] : (e - E);   // self-loops appended
    atomicAdd(&deg[dst], 1);
}

__global__ __launch_bounds__(1024) void k_scan1(const int* __restrict__ deg,
                                                int* __restrict__ rowstart,
                                                int* __restrict__ bsum, int n) {
    __shared__ int buf[1024];
    int tid = threadIdx.x, i = blockIdx.x * 1024 + tid;
    int v = (i < n) ? deg[i] : 0;
    buf[tid] = v;
    __syncthreads();
    for (int off = 1; off < 1024; off <<= 1) {
        int t = (tid >= off) ? buf[tid - off] : 0;
        __syncthreads();
        buf[tid] += t;
        __syncthreads();
    }
    if (i < n) rowstart[i] = buf[tid] - v;     // local exclusive
    if (tid == 1023) bsum[blockIdx.x] = buf[1023];
}

__global__ void k_scan2(const int* __restrict__ bsum, int* __restrict__ bcar,
                        int* __restrict__ rowstart, int nb, int n) {
    int lane = threadIdx.x;
    int v = (lane < nb) ? bsum[lane] : 0;
    int s = v;
    #pragma unroll
    for (int off = 1; off < 64; off <<= 1) {
        int t = __shfl_up(s, off);
        if (lane >= off) s += t;
    }
    if (lane < nb) bcar[lane] = s - v;
    if (lane == 63) rowstart[n] = s;
}

__global__ __launch_bounds__(1024) void k_scan3(int* __restrict__ rowstart,
                                                const int* __restrict__ bcar,
                                                int* __restrict__ cur, int n) {
    int i = blockIdx.x * 1024 + threadIdx.x;
    if (i < n) {
        int r = rowstart[i] + bcar[blockIdx.x];
        rowstart[i] = r;
        cur[i] = r;
    }
}

__global__ void k_fill(const int* __restrict__ ei, int* __restrict__ cur,
                       unsigned short* __restrict__ esrc, int E, int N) {
    int e = blockIdx.x * blockDim.x + threadIdx.x;
    if (e >= E + N) return;
    int src, dst;
    if (e < E) { src = ei[e]; dst = ei[E + e]; }
    else       { src = e - E; dst = e - E; }
    int pos = atomicAdd(&cur[dst], 1);
    esrc[pos] = (unsigned short)src;           // N < 65536
}

// ---------------- GEMM0 + fused att0 ----------------
// A-frag: lane holds A[m=lane&15][k=(lane>>4)*8+j]; B-frag: B[k][n=lane&15]
// C/D  : col=lane&15, row=(lane>>4)*4+reg  (m89-verified)
// a_src/a_dst accumulate from f32 acc: head = ct>>1 is wave-uniform.

__global__ __launch_bounds__(256) void k_gemm0(
    const float* __restrict__ x,
    const short* __restrict__ Wc0, const short* __restrict__ lWc0,
    const float* __restrict__ as0, const float* __restrict__ ad0,
    __hip_bfloat16* __restrict__ h0, __hip_bfloat16* __restrict__ skipb,
    float* __restrict__ a0s, float* __restrict__ a0d, int N) {
    int wv = threadIdx.x >> 6, lane = threadIdx.x & 63;
    int rowbase = blockIdx.x * 64 + wv * 16;
    int m = lane & 15, q = lane >> 4;
    int arow = rowbase + m; if (arow >= N) arow = N - 1;
    bf8_t a[4];
    #pragma unroll
    for (int kb = 0; kb < 4; kb++) {
        const float4* px = (const float4*)(x + (size_t)arow * 128 + kb * 32 + q * 8);
        float4 lo = px[0], hi = px[1];
        bf8_t f;
        f[0] = f2bf(lo.x); f[1] = f2bf(lo.y); f[2] = f2bf(lo.z); f[3] = f2bf(lo.w);
        f[4] = f2bf(hi.x); f[5] = f2bf(hi.y); f[6] = f2bf(hi.z); f[7] = f2bf(hi.w);
        a[kb] = f;
    }
    float sacc[4][4], dacc[4][4];
    #pragma unroll
    for (int h = 0; h < 4; h++)
        #pragma unroll
        for (int r = 0; r < 4; r++) { sacc[h][r] = 0.f; dacc[h][r] = 0.f; }

    for (int ct = 0; ct < 16; ct++) {
        const short* Wp = (ct < 8) ? Wc0 : lWc0;
        int cb = (ct & 7) * 16;
        f4_t acc = {0.f, 0.f, 0.f, 0.f};
        #pragma unroll
        for (int kb = 0; kb < 4; kb++) {
            bf8_t b = *(const bf8_t*)(Wp + (size_t)(cb + m) * 128 + kb * 32 + q * 8);
            acc = __builtin_amdgcn_mfma_f32_16x16x32_bf16(a[kb], b, acc, 0, 0, 0);
        }
        if (ct < 8) {
            int hd = ct >> 1;
            float ws = as0[cb + m], wd = ad0[cb + m];
            #pragma unroll
            for (int r = 0; r < 4; r++) {
                sacc[hd][r] += acc[r] * ws;
                dacc[hd][r] += acc[r] * wd;
            }
        }
        #pragma unroll
        for (int r = 0; r < 4; r++) {
            int row = rowbase + q * 4 + r;
            if (row < N) {
                int col = cb + m;
                if (ct < 8) h0[(size_t)row * 128 + col]    = __float2bfloat16(acc[r]);
                else        skipb[(size_t)row * 128 + col] = __float2bfloat16(acc[r]);
            }
        }
    }
    // reduce over the 16 m-lanes (xor 1,2,4,8 stays within the 16-group)
    #pragma unroll
    for (int h = 0; h < 4; h++)
        #pragma unroll
        for (int r = 0; r < 4; r++) {
            float s = sacc[h][r], d = dacc[h][r];
            #pragma unroll
            for (int off = 1; off < 16; off <<= 1) {
                s += __shfl_xor(s, off);
                d += __shfl_xor(d, off);
            }
            sacc[h][r] = s; dacc[h][r] = d;
        }
    if (m < 4) {
        #pragma unroll
        for (int r = 0; r < 4; r++) {
            int row = rowbase + q * 4 + r;
            if (row < N) {
                float sv = (m == 0) ? sacc[0][r] : (m == 1) ? sacc[1][r]
                         : (m == 2) ? sacc[2][r] : sacc[3][r];
                float dv = (m == 0) ? dacc[0][r] : (m == 1) ? dacc[1][r]
                         : (m == 2) ? dacc[2][r] : dacc[3][r];
                a0s[row * 4 + m] = sv;
                a0d[row * 4 + m] = dv;
            }
        }
    }
}

// ---------------- GEMM1 + fused att1 ----------------

__global__ __launch_bounds__(256) void k_gemm1(
    const __hip_bfloat16* __restrict__ hin,
    const short* __restrict__ Wc1, const short* __restrict__ lWc1,
    const float* __restrict__ as1, const float* __restrict__ ad1,
    __hip_bfloat16* __restrict__ h1, float* __restrict__ skipb /* = d_out */,
    float* __restrict__ a1s, float* __restrict__ a1d, int N) {
    int wv = threadIdx.x >> 6, lane = threadIdx.x & 63;
    int rowbase = blockIdx.x * 64 + wv * 16;
    int m = lane & 15, q = lane >> 4;
    int arow = rowbase + m; if (arow >= N) arow = N - 1;
    const short* xs = (const short*)hin;
    bf8_t a[4];
    #pragma unroll
    for (int kb = 0; kb < 4; kb++)
        a[kb] = *(const bf8_t*)(xs + (size_t)arow * 128 + kb * 32 + q * 8);
    float sacc[4], dacc[4];
    #pragma unroll
    for (int r = 0; r < 4; r++) { sacc[r] = 0.f; dacc[r] = 0.f; }
    #pragma unroll
    for (int ct = 0; ct < 4; ct++) {
        const short* Wp = (ct < 2) ? Wc1 : lWc1;
        int cb = (ct & 1) * 16;
        f4_t acc = {0.f, 0.f, 0.f, 0.f};
        #pragma unroll
        for (int kb = 0; kb < 4; kb++) {
            bf8_t b = *(const bf8_t*)(Wp + (size_t)(cb + m) * 128 + kb * 32 + q * 8);
            acc = __builtin_amdgcn_mfma_f32_16x16x32_bf16(a[kb], b, acc, 0, 0, 0);
        }
        if (ct < 2) {
            float ws = as1[cb + m], wd = ad1[cb + m];
            #pragma unroll
            for (int r = 0; r < 4; r++) {
                sacc[r] += acc[r] * ws;
                dacc[r] += acc[r] * wd;
            }
        }
        #pragma unroll
        for (int r = 0; r < 4; r++) {
            int row = rowbase + q * 4 + r;
            if (row < N) {
                size_t idx = (size_t)row * 32 + cb + m;
                if (ct < 2) h1[idx] = __float2bfloat16(acc[r]);
                else        skipb[idx] = acc[r];
            }
        }
    }
    #pragma unroll
    for (int r = 0; r < 4; r++) {
        float s = sacc[r], d = dacc[r];
        #pragma unroll
        for (int off = 1; off < 16; off <<= 1) {
            s += __shfl_xor(s, off);
            d += __shfl_xor(d, off);
        }
        if (m == 0) {
            int row = rowbase + q * 4 + r;
            if (row < N) { a1s[row] = s; a1d[row] = d; }
        }
    }
}

// ---------------- aggregation ----------------

// one wave per node; lane handles channels 2*lane, 2*lane+1; head = lane>>4
__global__ __launch_bounds__(256) void k_agg0(
    const int* __restrict__ rowstart, const unsigned short* __restrict__ esrc,
    const unsigned int* __restrict__ h0u,              // h0 packed bf16x2
    const float* __restrict__ a0s, const float* __restrict__ a0d,
    const float* __restrict__ bias0, const float* __restrict__ linb0,
    unsigned int* __restrict__ h1in_u,                 // in: skip0 bf16, out: ELU result
    int n) {
    int node = (blockIdx.x * 256 + threadIdx.x) >> 6;
    int lane = threadIdx.x & 63;
    if (node >= n) return;
    int hd = lane >> 4;
    float ad = a0d[node * 4 + hd];
    int s0 = rowstart[node], s1 = rowstart[node + 1];
    float den = 0.f, acc0 = 0.f, acc1 = 0.f;
    float denb = 0.f, acc0b = 0.f, acc1b = 0.f;
    int i = s0;
    for (; i + 7 < s1; i += 8) {
        int s[8]; float e[8]; unsigned int p[8];
        #pragma unroll
        for (int j = 0; j < 8; j++) s[j] = esrc[i + j];
        #pragma unroll
        for (int j = 0; j < 8; j++) e[j] = a0s[s[j] * 4 + hd] + ad;
        #pragma unroll
        for (int j = 0; j < 8; j++) p[j] = h0u[(size_t)s[j] * 64 + lane];
        #pragma unroll
        for (int j = 0; j < 8; j++) {
            float wgt = lrexp(e[j]);
            if (j & 1) { denb += wgt; acc0b += wgt * blo(p[j]); acc1b += wgt * bhi(p[j]); }
            else       { den  += wgt; acc0  += wgt * blo(p[j]); acc1  += wgt * bhi(p[j]); }
        }
    }
    for (; i < s1; i++) {
        int s = esrc[i];
        float wgt = lrexp(a0s[s * 4 + hd] + ad);
        unsigned int p = h0u[(size_t)s * 64 + lane];
        den += wgt; acc0 += wgt * blo(p); acc1 += wgt * bhi(p);
    }
    den += denb; acc0 += acc0b; acc1 += acc1b;
    float inv = 1.0f / (den + 1e-16f);
    int c0 = lane * 2;
    unsigned int sp = h1in_u[(size_t)node * 64 + lane];   // skip0 (bf16 pair)
    float o0 = acc0 * inv + blo(sp) + bias0[c0]     + linb0[c0];
    float o1 = acc1 * inv + bhi(sp) + bias0[c0 + 1] + linb0[c0 + 1];
    o0 = (o0 > 0.f) ? o0 : (__expf(o0) - 1.f);  // ELU
    o1 = (o1 > 0.f) ? o1 : (__expf(o1) - 1.f);
    unsigned int r0 = (unsigned int)(unsigned short)f2bf(o0);
    unsigned int r1 = (unsigned int)(unsigned short)f2bf(o1);
    h1in_u[(size_t)node * 64 + lane] = r0 | (r1 << 16);
}

// one wave per node; lanes 0-31 / 32-63 each take half the edge list (stride 2),
// channel c = lane&31; halves combined via shfl_xor(32). d_out holds skip1 (f32).
__global__ __launch_bounds__(256) void k_agg1(
    const int* __restrict__ rowstart, const unsigned short* __restrict__ esrc,
    const __hip_bfloat16* __restrict__ h1,
    const float* __restrict__ a1s, const float* __restrict__ a1d,
    const float* __restrict__ bias1, const float* __restrict__ linb1,
    float* __restrict__ out, int n) {
    int node = (blockIdx.x * 256 + threadIdx.x) >> 6;
    int lane = threadIdx.x & 63;
    if (node >= n) return;
    int c = lane & 31, half = lane >> 5;
    float ad = a1d[node];
    int s0 = rowstart[node], s1 = rowstart[node + 1];
    const unsigned short* h1u = (const unsigned short*)h1;
    float den = 0.f, acc = 0.f;
    int i = s0 + half;
    for (; i + 6 < s1; i += 8) {                 // 4 edges per half per iter
        int sA = esrc[i], sB = esrc[i + 2], sC = esrc[i + 4], sD = esrc[i + 6];
        float eA = a1s[sA] + ad, eB = a1s[sB] + ad, eC = a1s[sC] + ad, eD = a1s[sD] + ad;
        unsigned int hA = h1u[(size_t)sA * 32 + c];
        unsigned int hB = h1u[(size_t)sB * 32 + c];
        unsigned int hC = h1u[(size_t)sC * 32 + c];
        unsigned int hD = h1u[(size_t)sD * 32 + c];
        float wA = lrexp(eA), wB = lrexp(eB), wC = lrexp(eC), wD = lrexp(eD);
        den += (wA + wB) + (wC + wD);
        acc += wA * __uint_as_float(hA << 16) + wB * __uint_as_float(hB << 16)
             + wC * __uint_as_float(hC << 16) + wD * __uint_as_float(hD << 16);
    }
    for (; i < s1; i += 2) {
        int s = esrc[i];
        float wgt = lrexp(a1s[s] + ad);
        den += wgt;
        acc += wgt * __uint_as_float((unsigned int)h1u[(size_t)s * 32 + c] << 16);
    }
    acc += __shfl_xor(acc, 32);
    den += __shfl_xor(den, 32);
    if (lane < 32) {
        size_t idx = (size_t)node * 32 + c;
        out[idx] = acc / (den + 1e-16f) + out[idx] + bias1[c] + linb1[c];
    }
}

// ---------------- launch ----------------

extern "C" void kernel_launch(void* const* d_in, const int* in_sizes, int n_in,
                              void* d_out, int out_size, void* d_ws, size_t ws_size,
                              hipStream_t stream) {
    const float* x   = (const float*)d_in[0];
    const int*   ei  = (const int*)d_in[1];
    const float* W0  = (const float*)d_in[2];
    const float* as0 = (const float*)d_in[3];
    const float* ad0 = (const float*)d_in[4];
    const float* b0  = (const float*)d_in[5];
    const float* lW0 = (const float*)d_in[6];
    const float* lb0 = (const float*)d_in[7];
    const float* W1  = (const float*)d_in[8];
    const float* as1 = (const float*)d_in[9];
    const float* ad1 = (const float*)d_in[10];
    const float* b1  = (const float*)d_in[11];
    const float* lW1 = (const float*)d_in[12];
    const float* lb1 = (const float*)d_in[13];
    float* out = (float*)d_out;

    const int N = in_sizes[0] / 128;
    const int E = in_sizes[1] / 2;
    const int T = E + N;
    const int NB = (N + 1023) / 1024;

    // workspace carve-up (256B aligned), ~29.5 MB
    char* w = (char*)d_ws;
    auto alloc = [&](size_t bytes) -> char* {
        char* p = w; w += (bytes + 255) / 256 * 256; return p;
    };
    int* rowstart  = (int*)alloc((size_t)(N + 1) * 4);
    int* cnt       = (int*)alloc((size_t)N * 4);          // deg, then fill-cursor
    int* bsum      = (int*)alloc(64 * 4);
    int* bcar      = (int*)alloc(64 * 4);
    unsigned short* esrc = (unsigned short*)alloc((size_t)T * 2);
    float* aS      = (float*)alloc((size_t)N * 4 * 4);    // layer0 [N,4]; layer1 [N]
    float* aD      = (float*)alloc((size_t)N * 4 * 4);
    __hip_bfloat16* hbuf = (__hip_bfloat16*)alloc((size_t)N * 128 * 2); // h0 / h1
    __hip_bfloat16* h1in = (__hip_bfloat16*)alloc((size_t)N * 128 * 2); // skip0 -> ELU
    short* Wc0  = (short*)alloc(16384 * 2);
    short* lWc0 = (short*)alloc(16384 * 2);
    short* Wc1  = (short*)alloc(4096 * 2);
    short* lWc1 = (short*)alloc(4096 * 2);

    // weight prep (independent of CSR)
    k_prep<<<160, 256, 0, stream>>>(W0, lW0, W1, lW1, Wc0, lWc0, Wc1, lWc1);

    // CSR build
    k_zero<<<(N + 255) / 256, 256, 0, stream>>>(cnt, N);
    k_count<<<(T + 255) / 256, 256, 0, stream>>>(ei, cnt, E, N);
    k_scan1<<<NB, 1024, 0, stream>>>(cnt, rowstart, bsum, N);
    k_scan2<<<1, 64, 0, stream>>>(bsum, bcar, rowstart, NB, N);
    k_scan3<<<NB, 1024, 0, stream>>>(rowstart, bcar, cnt, N);
    k_fill<<<(T + 255) / 256, 256, 0, stream>>>(ei, cnt, esrc, E, N);

    // layer 0 (att fused into gemm)
    k_gemm0<<<(N + 63) / 64, 256, 0, stream>>>(x, Wc0, lWc0, as0, ad0,
                                               hbuf, h1in, aS, aD, N);
    k_agg0<<<(N + 3) / 4, 256, 0, stream>>>(rowstart, esrc, (const unsigned int*)hbuf,
                                            aS, aD, b0, lb0, (unsigned int*)h1in, N);
    // layer 1 (h1 reuses hbuf; skip1 lives in d_out f32; att fused)
    k_gemm1<<<(N + 63) / 64, 256, 0, stream>>>(h1in, Wc1, lWc1, as1, ad1,
                                               hbuf, out, aS, aD, N);
    k_agg1<<<(N + 3) / 4, 256, 0, stream>>>(rowstart, esrc, hbuf, aS, aD,
                                            b1, lb1, out, N);
}